// Round 6
// baseline (578.041 us; speedup 1.0000x reference)
//
#include <hip/hip_runtime.h>

// Outputs are FLOAT32 (reference output dtype), not bf16 — R5 decoded this:
// bf16 writes produced error 3.3978 == max|efeat| bleeding into X's f32 region.
// Pipeline below is the R2/R3 hardware-verified math with f32 I/O.

#define NPB 8

__device__ inline void atomAddF(float* p, float v) {
#if defined(__HIP_PLATFORM_AMD__)
    unsafeAtomicAdd(p, v);
#else
    atomicAdd(p, v);
#endif
}

__global__ void zero_acc(float* __restrict__ acc, int n) {
    int i = blockIdx.x * blockDim.x + threadIdx.x;
    if (i < n) acc[i] = 0.0f;
}

// ---------------------------------------------------------------------------
// Edge kernel: half-wave (32 threads) per edge; thread u = channel u.
// Weights staged in LDS; edge row broadcast via __shfl(width 32).
// ---------------------------------------------------------------------------
__global__ __launch_bounds__(256, 4) void edge_f32_kernel(
    const int*   __restrict__ node_type,
    const float* __restrict__ edge_attr,    // [E][64]
    const float* __restrict__ bond_dist,    // [E]
    const float* __restrict__ bond_vec,     // [E][3]
    const int*   __restrict__ src,
    const int*   __restrict__ dst,
    const float* __restrict__ emb,          // [95][32]
    const float* __restrict__ Wd1, const float* __restrict__ bd1,
    const float* __restrict__ Wd2, const float* __restrict__ bd2,
    const float* __restrict__ Wd3, const float* __restrict__ bd3,
    const float* __restrict__ We2, const float* __restrict__ be2,
    const float* __restrict__ We3, const float* __restrict__ be3,
    float* __restrict__ acc,                // [N][10][32] fp32, pre-zeroed
    float* __restrict__ efeat,              // [E][32]
    int E)
{
    __shared__ float sW[5][64][32];   // 0:Wd1 1:Wd2 2:Wd3 3:We3 4:We2
    __shared__ float sB[5][32];
    const int tid = threadIdx.x;
    for (int i = tid; i < 5 * 2048; i += 256) {
        const int m = i >> 11, r = i & 2047;
        const float* W = (m == 0) ? Wd1 : (m == 1) ? Wd2 : (m == 2) ? Wd3 : (m == 3) ? We3 : We2;
        sW[m][r >> 5][r & 31] = W[r];
    }
    if (tid < 32) {
        sB[0][tid] = bd1[tid]; sB[1][tid] = bd2[tid]; sB[2][tid] = bd3[tid];
        sB[3][tid] = be3[tid]; sB[4][tid] = be2[tid];
    }
    __syncthreads();

    const int u = tid & 31;
    const int grp = (blockIdx.x * blockDim.x + tid) >> 5;
    const int ngrp = (gridDim.x * blockDim.x) >> 5;

    for (int e = grp; e < E; e += ngrp) {
        const int ts = node_type[src[e]];
        const int td = node_type[dst[e]];
        const float xlo = edge_attr[(size_t)e * 64 + u];
        const float xhi = edge_attr[(size_t)e * 64 + 32 + u];
        const float zs = emb[ts * 32 + u];
        const float zd = emb[td * 32 + u];
        float a1 = sB[0][u], a2 = sB[1][u], a3 = sB[2][u], a4 = sB[3][u], az = sB[4][u];
#pragma unroll
        for (int k = 0; k < 32; ++k) {
            const float xk  = __shfl(xlo, k, 32);
            const float xk2 = __shfl(xhi, k, 32);
            const float zk  = __shfl(zs, k, 32);
            const float zk2 = __shfl(zd, k, 32);
            a1 += xk * sW[0][k][u] + xk2 * sW[0][k + 32][u];
            a2 += xk * sW[1][k][u] + xk2 * sW[1][k + 32][u];
            a3 += xk * sW[2][k][u] + xk2 * sW[2][k + 32][u];
            a4 += xk * sW[3][k][u] + xk2 * sW[3][k + 32][u];
            az += zk * sW[4][k][u] + zk2 * sW[4][k + 32][u];
        }
        const float d = bond_dist[e];
        const float C = (d <= 5.0f) ? 0.5f * (cosf(3.14159265358979323846f * d / 5.0f) + 1.0f) : 0.0f;
        float v0 = bond_vec[3 * (size_t)e + 0];
        float v1 = bond_vec[3 * (size_t)e + 1];
        float v2 = bond_vec[3 * (size_t)e + 2];
        const float inv = 1.0f / sqrtf(v0 * v0 + v1 * v1 + v2 * v2);
        v0 *= inv; v1 *= inv; v2 *= inv;
        const float tr3 = (v0 * v0 + v1 * v1 + v2 * v2) * (1.0f / 3.0f);
        const float s00 = v0 * v0 - tr3, s11 = v1 * v1 - tr3, s22 = v2 * v2 - tr3;
        const float s01 = v0 * v1, s02 = v0 * v2, s12 = v1 * v2;

        const float w1 = a1 * C, w2 = a2 * C, w3 = a3 * C;
        const float fI = az * w1, fA = az * w2, fS = az * w3;
        efeat[(size_t)e * 32 + u] = a4;
        float* ap = acc + (size_t)dst[e] * 320 + u;
        atomAddF(ap,       fI);
        atomAddF(ap + 32,  fA * v0);
        atomAddF(ap + 64,  fA * v1);
        atomAddF(ap + 96,  fA * v2);
        atomAddF(ap + 128, fS * s00);
        atomAddF(ap + 160, fS * s01);
        atomAddF(ap + 192, fS * s02);
        atomAddF(ap + 224, fS * s11);
        atomAddF(ap + 256, fS * s12);
        atomAddF(ap + 288, fS * s22);
    }
}

// ---------------------------------------------------------------------------
// Node kernel: 8 nodes/block, 32 threads (=channels) per node.
// ---------------------------------------------------------------------------
__global__ __launch_bounds__(256) void node_kernel(
    const float* __restrict__ acc,          // [N][10][32]
    const float* __restrict__ Wt0, const float* __restrict__ Wt1, const float* __restrict__ Wt2,
    const float* __restrict__ Ws1, const float* __restrict__ bs1,
    const float* __restrict__ Ws2, const float* __restrict__ bs2,
    const float* __restrict__ lng, const float* __restrict__ lnb,
    float* __restrict__ xout,               // [N][32][3][3]
    int N)
{
    __shared__ float wt[3][32][32];
    __shared__ float ws1[32][64];
    __shared__ float ws2[64][96];
    __shared__ float sb1[64], sb2[96], sg[32], sbv[32];
    __shared__ float accS[NPB][10][32];
    __shared__ float nrmS[NPB][32];
    __shared__ float h1S[NPB][64];

    const int tid = threadIdx.x;
    for (int i = tid; i < 1024; i += 256) wt[0][i >> 5][i & 31] = Wt0[i];
    for (int i = tid; i < 1024; i += 256) wt[1][i >> 5][i & 31] = Wt1[i];
    for (int i = tid; i < 1024; i += 256) wt[2][i >> 5][i & 31] = Wt2[i];
    for (int i = tid; i < 2048; i += 256) ws1[i >> 6][i & 63] = Ws1[i];
    for (int i = tid; i < 6144; i += 256) ws2[i / 96][i % 96] = Ws2[i];
    if (tid < 64) sb1[tid] = bs1[tid];
    if (tid < 96) sb2[tid] = bs2[tid];
    if (tid < 32) { sg[tid] = lng[tid]; sbv[tid] = lnb[tid]; }
    __syncthreads();

    const int ln_ = tid >> 5, u = tid & 31;
    const int n = blockIdx.x * NPB + ln_;
    const bool valid = n < N;

    float c0 = 0, a0 = 0, a1 = 0, a2 = 0, s00 = 0, s01 = 0, s02 = 0, s11 = 0, s12 = 0, s22 = 0;
    if (valid) {
        const float* ap = acc + (size_t)n * 320 + u;
        c0 = ap[0];  a0 = ap[32];  a1 = ap[64];  a2 = ap[96];
        s00 = ap[128]; s01 = ap[160]; s02 = ap[192];
        s11 = ap[224]; s12 = ap[256]; s22 = ap[288];
    }
    accS[ln_][0][u] = c0;  accS[ln_][1][u] = a0;  accS[ln_][2][u] = a1;  accS[ln_][3][u] = a2;
    accS[ln_][4][u] = s00; accS[ln_][5][u] = s01; accS[ln_][6][u] = s02;
    accS[ln_][7][u] = s11; accS[ln_][8][u] = s12; accS[ln_][9][u] = s22;

    float m00 = c0 + s00, m11 = c0 + s11, m22 = c0 + s22;
    float nrm = m00 * m00 + m11 * m11 + m22 * m22
              + 2.0f * (s01 * s01 + a2 * a2 + s02 * s02 + a1 * a1 + s12 * s12 + a0 * a0);

    float sum = nrm;
#pragma unroll
    for (int o = 16; o >= 1; o >>= 1) sum += __shfl_xor(sum, o, 32);
    float mu = sum * (1.0f / 32.0f);
    float dv = nrm - mu;
    float vs = dv * dv;
#pragma unroll
    for (int o = 16; o >= 1; o >>= 1) vs += __shfl_xor(vs, o, 32);
    float var = vs * (1.0f / 32.0f);
    float nl = dv * rsqrtf(var + 1e-5f) * sg[u] + sbv[u];
    nrmS[ln_][u] = nl;
    __syncthreads();

    float h1a = sb1[u], h1b = sb1[u + 32];
#pragma unroll
    for (int k = 0; k < 32; ++k) {
        float x = nrmS[ln_][k];
        h1a += x * ws1[k][u];
        h1b += x * ws1[k][u + 32];
    }
    h1a = h1a / (1.0f + __expf(-h1a));
    h1b = h1b / (1.0f + __expf(-h1b));
    h1S[ln_][u] = h1a; h1S[ln_][u + 32] = h1b;
    __syncthreads();

    float f0 = sb2[3 * u], f1 = sb2[3 * u + 1], f2 = sb2[3 * u + 2];
#pragma unroll
    for (int k = 0; k < 64; ++k) {
        float h = h1S[ln_][k];
        f0 += h * ws2[k][3 * u];
        f1 += h * ws2[k][3 * u + 1];
        f2 += h * ws2[k][3 * u + 2];
    }
    f0 = f0 / (1.0f + __expf(-f0));
    f1 = f1 / (1.0f + __expf(-f1));
    f2 = f2 / (1.0f + __expf(-f2));

    float m0 = 0, ma0 = 0, ma1 = 0, ma2 = 0;
    float ms00 = 0, ms01 = 0, ms02 = 0, ms11 = 0, ms12 = 0, ms22 = 0;
#pragma unroll
    for (int k = 0; k < 32; ++k) {
        float w0 = wt[0][k][u], w1 = wt[1][k][u], w2 = wt[2][k][u];
        m0   += accS[ln_][0][k] * w0;
        ma0  += accS[ln_][1][k] * w1;
        ma1  += accS[ln_][2][k] * w1;
        ma2  += accS[ln_][3][k] * w1;
        ms00 += accS[ln_][4][k] * w2;
        ms01 += accS[ln_][5][k] * w2;
        ms02 += accS[ln_][6][k] * w2;
        ms11 += accS[ln_][7][k] * w2;
        ms12 += accS[ln_][8][k] * w2;
        ms22 += accS[ln_][9][k] * w2;
    }
    if (valid) {
        float* xp = xout + (size_t)n * 288 + u * 9;
        xp[0] = f0 * m0 + f2 * ms00;
        xp[1] = f1 * (-ma2) + f2 * ms01;
        xp[2] = f1 * ( ma1) + f2 * ms02;
        xp[3] = f1 * ( ma2) + f2 * ms01;
        xp[4] = f0 * m0 + f2 * ms11;
        xp[5] = f1 * (-ma0) + f2 * ms12;
        xp[6] = f1 * (-ma1) + f2 * ms02;
        xp[7] = f1 * ( ma0) + f2 * ms12;
        xp[8] = f0 * m0 + f2 * ms22;
    }
}

extern "C" void kernel_launch(void* const* d_in, const int* in_sizes, int n_in,
                              void* d_out, int out_size, void* d_ws, size_t ws_size,
                              hipStream_t stream) {
    const int N = in_sizes[0];
    const int E = in_sizes[2];

    float* acc = (float*)d_ws;                 // N*10*32 fp32 = 25.6 MB
    float* xout  = (float*)d_out;              // [N][32][3][3] f32
    float* efeat = xout + (size_t)N * 288;     // [E][32] f32

    const int accElems = N * 320;
    zero_acc<<<(accElems + 255) / 256, 256, 0, stream>>>(acc, accElems);

    edge_f32_kernel<<<1024, 256, 0, stream>>>(
        (const int*)d_in[0], (const float*)d_in[1], (const float*)d_in[2],
        (const float*)d_in[3], (const int*)d_in[4], (const int*)d_in[5],
        (const float*)d_in[6],
        (const float*)d_in[7],  (const float*)d_in[8],
        (const float*)d_in[9],  (const float*)d_in[10],
        (const float*)d_in[11], (const float*)d_in[12],
        (const float*)d_in[13], (const float*)d_in[14],
        (const float*)d_in[15], (const float*)d_in[16],
        acc, efeat, E);

    node_kernel<<<(N + NPB - 1) / NPB, 256, 0, stream>>>(
        acc,
        (const float*)d_in[17], (const float*)d_in[18], (const float*)d_in[19],
        (const float*)d_in[20], (const float*)d_in[21],
        (const float*)d_in[22], (const float*)d_in[23],
        (const float*)d_in[24], (const float*)d_in[25],
        xout, N);
}